// Round 1
// baseline (371.430 us; speedup 1.0000x reference)
//
#include <hip/hip_runtime.h>
#include <hip/hip_cooperative_groups.h>
#include <math.h>

namespace cg = cooperative_groups;

// ALCOVE cell: B=256, D=64, H=2048, O=32
// RHO=2, TAU=1, BETA=6.5, GAMMA=0, PHI=2, LAM_A=0.001, LAM_W=0.003
//
// R4: fuse k1+k2+k3 into ONE cooperative kernel with two grid.sync()s.
//   - s/r never leave LDS (kills the 16 MB s_all/r_all round trip)
//   - no inter-kernel drain gaps
//   - block (b,p) re-reads in phase 2 the exact assoc slice it read in
//     phase 1 -> partial per-XCD L2 reuse, rest L3
//   - 1024 blocks x 256 thr, __launch_bounds__(256,4): VGPR<=128 ->
//     exactly 4 blocks/CU resident = whole grid co-resident (coop-valid)
//
// ws layout (floats):
//   ct         [D*H]      = 131072
//   px         [B*4*O]    = 32768
//   gatt_part  [B*4*D]    = 65536

#define BB 256
#define DD 64
#define HH 2048
#define OO 32
#define NP 4            // pair-slices per batch row
#define HP (HH / NP)    // 512 h per block
#define BETA 6.5f
#define PHI 2.0f
#define LAM_A 0.001f
#define LAM_W 0.003f
#define NT 256

__global__ __launch_bounds__(NT) void k0_transpose(
    const float* __restrict__ coords, float* __restrict__ ct)
{
    int idx = blockIdx.x * NT + threadIdx.x;   // 0 .. D*H-1, ct-linear
    int d = idx >> 11;                         // / HH
    int h = idx & (HH - 1);
    ct[idx] = coords[h * DD + d];
}

__global__ __launch_bounds__(NT, 4) void k_fused(
    const float* __restrict__ z,
    const float* __restrict__ one_hot,
    const float* __restrict__ att,
    const float* __restrict__ assoc,
    const float* __restrict__ coords,
    const float* __restrict__ ct,
    float* __restrict__ px,
    float* __restrict__ gatt_part,
    float* __restrict__ out)
{
    __shared__ float2 za[DD];          // (z_d, att_d)
    __shared__ float  s_loc[HP];       // similarity s
    __shared__ float  rc_loc[HP];      // r = -beta*s/(2d), later coeff = r*g_s
    __shared__ float4 red4[NT];        // reduction scratch
    __shared__ float  gx_s[OO];

    const int b    = blockIdx.x >> 2;
    const int p    = blockIdx.x & 3;
    const int base = p * HP;
    const int t    = threadIdx.x;

    if (t < DD)
        za[t] = make_float2(z[b * DD + t], att[b * DD + t]);
    __syncthreads();

    // ---- phase 1a: distance/similarity for 2 sub-slices of 256 h ----
    #pragma unroll
    for (int ss = 0; ss < 2; ++ss) {
        const int h = base + ss * NT + t;
        float S = 0.0f;
        const float* ctp = ct + h;
        #pragma unroll 8
        for (int d = 0; d < DD; ++d) {
            float2 pz = za[d];                 // broadcast ds_read_b64
            float c = ctp[d * HH];             // coalesced, L2-resident
            float diff = pz.x - c;
            S = fmaf(pz.y * diff, diff, S);
        }
        S = S < 0.0f ? 0.0f : S;
        float dd = sqrtf(S);
        float sh = expf(-BETA * dd);
        s_loc[ss * NT + t]  = sh;
        rc_loc[ss * NT + t] = (dd > 0.0f) ? (-BETA * sh / (2.0f * dd)) : 0.0f;
    }
    __syncthreads();

    // ---- phase 1b: partial x_out over this 512-h slice (float4 over o) ----
    const int o4 = t & 7;       // float4 column
    const int hl = t >> 3;      // 0..31
    const float4* assoc4 = (const float4*)(assoc + (size_t)b * HH * OO);

    float4 acc = make_float4(0.f, 0.f, 0.f, 0.f);
    #pragma unroll 4
    for (int chunk = 0; chunk < HP / 32; ++chunk) {   // 16 chunks
        int hloc = chunk * 32 + hl;
        float s2 = s_loc[hloc];
        float4 a = assoc4[(base + hloc) * (OO / 4) + o4];
        acc.x = fmaf(s2, a.x, acc.x);
        acc.y = fmaf(s2, a.y, acc.y);
        acc.z = fmaf(s2, a.z, acc.z);
        acc.w = fmaf(s2, a.w, acc.w);
    }
    red4[t] = acc;
    __syncthreads();

    if (t < OO) {
        const float* red = (const float*)red4;
        const int b4 = t >> 2, comp = t & 3;
        float x = 0.0f;
        #pragma unroll 8
        for (int g = 0; g < 32; ++g)
            x += red[(g * 8 + b4) * 4 + comp];
        px[(b * NP + p) * OO + t] = x;
    }

    cg::this_grid().sync();

    // ---- phase 2a: gx from full x_out (redundant per block, tiny) ----
    if (t < OO) {
        float x = 0.0f;
        #pragma unroll
        for (int q = 0; q < NP; ++q)
            x += px[(b * NP + q) * OO + t];
        float oh = one_hot[b * OO + t];
        float tmin = fminf(-1.0f, x);
        float tmax = fmaxf(1.0f, x);
        float teacher = tmin - oh * tmin + oh * tmax;
        gx_s[t] = (2.0f / OO) * (x - teacher);
        if (p == 0)
            out[b * OO + t] = PHI * x;                   // output 0
    }
    __syncthreads();

    // ---- phase 2b: assoc update + g_s -> coeff (in-place on rc_loc) ----
    const float4 gxv = ((const float4*)gx_s)[o4];
    float4* out_assoc4 = (float4*)(out + BB * OO + BB * DD) + (size_t)b * HH * (OO / 4);

    #pragma unroll 4
    for (int chunk = 0; chunk < HP / 32; ++chunk) {
        int hloc = chunk * 32 + hl;
        float sh = s_loc[hloc];
        float4 a = assoc4[(base + hloc) * (OO / 4) + o4];
        float w = LAM_W * sh;
        float4 na;
        na.x = fmaf(-w, gxv.x, a.x);
        na.y = fmaf(-w, gxv.y, a.y);
        na.z = fmaf(-w, gxv.z, a.z);
        na.w = fmaf(-w, gxv.w, a.w);
        out_assoc4[(base + hloc) * (OO / 4) + o4] = na;  // output 2

        float part = a.x * gxv.x + a.y * gxv.y + a.z * gxv.z + a.w * gxv.w;
        part += __shfl_xor(part, 1, 64);
        part += __shfl_xor(part, 2, 64);
        part += __shfl_xor(part, 4, 64);
        if (o4 == 0)
            rc_loc[hloc] *= part;          // coeff = r * g_s
    }
    __syncthreads();

    // ---- phase 2c: partial g_att over this slice (lane == d) ----
    {
        const int lane = t & 63, wave = t >> 6;
        const float zd = za[lane].x;
        float* red = (float*)red4;
        float ga = 0.0f;
        #pragma unroll 4
        for (int i = 0; i < HP / 4; ++i) {            // 128 h per wave
            int hloc = wave * (HP / 4) + i;
            float cf = rc_loc[hloc];                  // broadcast
            float c = coords[(size_t)(base + hloc) * DD + lane];  // coalesced row
            float diff = zd - c;
            ga = fmaf(cf * diff, diff, ga);
        }
        red[t] = ga;
    }
    __syncthreads();
    if (t < DD) {
        const float* red = (const float*)red4;
        float g = red[t] + red[64 + t] + red[128 + t] + red[192 + t];
        gatt_part[(b * NP + p) * DD + t] = g;
    }

    cg::this_grid().sync();

    // ---- phase 3: finalize new_attention (output 1), first 64 blocks ----
    if (blockIdx.x < (BB * DD) / NT) {
        int idx = blockIdx.x * NT + t;
        int bb = idx >> 6, d = idx & 63;
        float g = 0.0f;
        #pragma unroll
        for (int q = 0; q < NP; ++q)
            g += gatt_part[(bb * NP + q) * DD + d];
        float na = att[bb * DD + d] - LAM_A * g;
        out[BB * OO + idx] = na > 0.0f ? na : 0.0f;
    }
}

extern "C" void kernel_launch(void* const* d_in, const int* in_sizes, int n_in,
                              void* d_out, int out_size, void* d_ws, size_t ws_size,
                              hipStream_t stream) {
    const float* z       = (const float*)d_in[0];
    const float* one_hot = (const float*)d_in[1];
    const float* att     = (const float*)d_in[2];
    const float* assoc   = (const float*)d_in[3];
    const float* coords  = (const float*)d_in[4];
    float* out = (float*)d_out;

    float* ws = (float*)d_ws;
    float* ct        = ws;                            // D*H
    float* px        = ct + DD * HH;                  // B*NP*O
    float* gatt_part = px + BB * NP * OO;             // B*NP*D

    k0_transpose<<<dim3((DD * HH) / NT), dim3(NT), 0, stream>>>(coords, ct);

    void* args[] = { (void*)&z, (void*)&one_hot, (void*)&att, (void*)&assoc,
                     (void*)&coords, (void*)&ct, (void*)&px, (void*)&gatt_part,
                     (void*)&out };
    hipLaunchCooperativeKernel((const void*)k_fused, dim3(BB * NP), dim3(NT),
                               args, 0, stream);
}

// Round 4
// 139.915 us; speedup vs baseline: 2.6547x; 2.6547x over previous
//
#include <hip/hip_runtime.h>
#include <math.h>

// ALCOVE cell: B=256, D=64, H=2048, O=32
// RHO=2, TAU=1, BETA=6.5, GAMMA=0, PHI=2, LAM_A=0.001, LAM_W=0.003
//
// R7: one block per batch row. 256 blocks x 1024 threads (16 waves/CU).
//   All cross-slice dependencies (the H-sum for gx) are now intra-block
//   __syncthreads — NO atomics, NO rendezvous, NO cooperative launch.
//   R5/R6 post-mortem: hand-rolled cross-XCD rendezvous failed
//   deterministically on the gatt handoff (out1 err 1.0, twice, two
//   different implementations) -> abandoned by construction.
//
//   Key win: each thread owns exactly 16 float4 of assoc; cached in
//   64 VGPRs across the gx barrier -> assoc read from HBM ONCE (R1
//   counters showed the 2nd pass as ~67MB extra traffic + latency).
//
// ws: ct [D*H] only (512 KB, L2-resident transpose of coords).

#define BB 256
#define DD 64
#define HH 2048
#define OO 32
#define BETA 6.5f
#define PHI 2.0f
#define LAM_A 0.001f
#define LAM_W 0.003f
#define NT0 256
#define NT 1024
#define NW (NT / 64)            // 16 waves
#define NCH (HH / (NT / 8))     // 16 assoc chunks per thread

__global__ __launch_bounds__(NT0) void k0_transpose(
    const float* __restrict__ coords, float* __restrict__ ct)
{
    int idx = blockIdx.x * NT0 + threadIdx.x;   // 0 .. D*H-1, ct-linear
    int d = idx >> 11;                          // / HH
    int h = idx & (HH - 1);
    ct[idx] = coords[h * DD + d];
}

__global__ __launch_bounds__(NT) void k_cell(
    const float* __restrict__ z,
    const float* __restrict__ one_hot,
    const float* __restrict__ att,
    const float* __restrict__ assoc,
    const float* __restrict__ coords,
    const float* __restrict__ ct,
    float* __restrict__ out)
{
    __shared__ float2 za[DD];           // (z_d, att_d)
    __shared__ float  s_loc[HH];        // 8 KB: similarity s
    __shared__ float  rc_loc[HH];       // 8 KB: r = -beta*s/(2d), then coeff
    __shared__ float  wredf[NW * OO];   // 2 KB: per-wave x_out partials
    __shared__ float  redf[NT];         // 4 KB: g_att reduction
    __shared__ float  gx_s[OO];

    const int b = blockIdx.x;
    const int t = threadIdx.x;

    if (t < DD)
        za[t] = make_float2(z[b * DD + t], att[b * DD + t]);
    __syncthreads();

    // ---- phase 1: distance/similarity for all 2048 h ----
    #pragma unroll
    for (int i = 0; i < HH / NT; ++i) {          // 2 rounds of 1024 h
        const int h = i * NT + t;
        float S = 0.0f;
        const float* ctp = ct + h;
        #pragma unroll 16
        for (int d = 0; d < DD; ++d) {
            float2 p = za[d];                    // broadcast ds_read_b64
            float c = ctp[d * HH];               // coalesced, L2-hit
            float diff = p.x - c;
            S = fmaf(p.y * diff, diff, S);
        }
        S = S < 0.0f ? 0.0f : S;
        float dd = sqrtf(S);
        float sh = expf(-BETA * dd);
        s_loc[h]  = sh;
        rc_loc[h] = (dd > 0.0f) ? (-BETA * sh / (2.0f * dd)) : 0.0f;
    }
    __syncthreads();

    // ---- phase 2: x_out pass; register-cache assoc (read HBM once) ----
    const int o4 = t & 7;        // float4 column (o = o4*4 + comp)
    const int hl = t >> 3;       // 0..127
    const float4* assoc4 = (const float4*)(assoc + (size_t)b * HH * OO);

    float4 areg[NCH];
    float4 acc = make_float4(0.f, 0.f, 0.f, 0.f);
    #pragma unroll
    for (int ch = 0; ch < NCH; ++ch) {           // 16 chunks, static idx
        int hloc = ch * (NT / 8) + hl;
        float4 a = assoc4[hloc * (OO / 4) + o4]; // coalesced 1KB/wave
        areg[ch] = a;
        float s2 = s_loc[hloc];
        acc.x = fmaf(s2, a.x, acc.x);
        acc.y = fmaf(s2, a.y, acc.y);
        acc.z = fmaf(s2, a.z, acc.z);
        acc.w = fmaf(s2, a.w, acc.w);
    }
    // reduce over the 8 hl-rows inside each wave (lane bits 3..5)
    #pragma unroll
    for (int m = 8; m <= 32; m <<= 1) {
        acc.x += __shfl_xor(acc.x, m, 64);
        acc.y += __shfl_xor(acc.y, m, 64);
        acc.z += __shfl_xor(acc.z, m, 64);
        acc.w += __shfl_xor(acc.w, m, 64);
    }
    if ((t & 63) < 8) {                          // lane o4 of each wave
        int w = t >> 6;
        wredf[w * OO + o4 * 4 + 0] = acc.x;
        wredf[w * OO + o4 * 4 + 1] = acc.y;
        wredf[w * OO + o4 * 4 + 2] = acc.z;
        wredf[w * OO + o4 * 4 + 3] = acc.w;
    }
    __syncthreads();

    // ---- gx + output 0 (t < 32; o == t) ----
    if (t < OO) {
        float x = 0.0f;
        #pragma unroll
        for (int w = 0; w < NW; ++w)
            x += wredf[w * OO + t];              // conflict-free row reads
        float oh = one_hot[b * OO + t];
        float tmin = fminf(-1.0f, x);
        float tmax = fmaxf(1.0f, x);
        float teacher = tmin - oh * tmin + oh * tmax;
        gx_s[t] = (2.0f / OO) * (x - teacher);
        out[b * OO + t] = PHI * x;               // output 0
    }
    __syncthreads();

    // ---- phase 3: assoc update from registers + g_s -> coeff ----
    const float4 gxv = ((const float4*)gx_s)[o4];
    float4* out_assoc4 = (float4*)(out + BB * OO + BB * DD)
                       + (size_t)b * HH * (OO / 4);

    #pragma unroll
    for (int ch = 0; ch < NCH; ++ch) {
        int hloc = ch * (NT / 8) + hl;
        float4 a = areg[ch];                     // from registers, no re-read
        float w = LAM_W * s_loc[hloc];
        float4 na;
        na.x = fmaf(-w, gxv.x, a.x);
        na.y = fmaf(-w, gxv.y, a.y);
        na.z = fmaf(-w, gxv.z, a.z);
        na.w = fmaf(-w, gxv.w, a.w);
        out_assoc4[hloc * (OO / 4) + o4] = na;   // output 2

        float part = a.x * gxv.x + a.y * gxv.y + a.z * gxv.z + a.w * gxv.w;
        part += __shfl_xor(part, 1, 64);
        part += __shfl_xor(part, 2, 64);
        part += __shfl_xor(part, 4, 64);
        if (o4 == 0)
            rc_loc[hloc] *= part;                // coeff = r * g_s
    }
    __syncthreads();

    // ---- phase 4: g_att + output 1, fully in-block ----
    {
        const int lane = t & 63, wv = t >> 6;
        const float zd = za[lane].x;
        float ga = 0.0f;
        #pragma unroll 8
        for (int i = 0; i < HH / NW; ++i) {      // 128 h per wave
            int hloc = wv * (HH / NW) + i;
            float cf = rc_loc[hloc];             // broadcast
            float c = coords[(size_t)hloc * DD + lane];  // coalesced row
            float diff = zd - c;
            ga = fmaf(cf * diff, diff, ga);
        }
        redf[t] = ga;
    }
    __syncthreads();
    if (t < DD) {
        float g = 0.0f;
        #pragma unroll
        for (int w = 0; w < NW; ++w)
            g += redf[w * 64 + t];               // conflict-free rows
        float na = att[b * DD + t] - LAM_A * g;
        out[BB * OO + b * DD + t] = na > 0.0f ? na : 0.0f;   // output 1
    }
}

extern "C" void kernel_launch(void* const* d_in, const int* in_sizes, int n_in,
                              void* d_out, int out_size, void* d_ws, size_t ws_size,
                              hipStream_t stream) {
    const float* z       = (const float*)d_in[0];
    const float* one_hot = (const float*)d_in[1];
    const float* att     = (const float*)d_in[2];
    const float* assoc   = (const float*)d_in[3];
    const float* coords  = (const float*)d_in[4];
    float* out = (float*)d_out;

    float* ct = (float*)d_ws;                    // D*H floats

    k0_transpose<<<dim3((DD * HH) / NT0), dim3(NT0), 0, stream>>>(coords, ct);
    k_cell<<<dim3(BB), dim3(NT), 0, stream>>>(z, one_hot, att, assoc,
                                              coords, ct, out);
}